// Round 3
// baseline (2228.224 us; speedup 1.0000x reference)
//
#include <hip/hip_runtime.h>
#include <hip/hip_bf16.h>

using bf16 = __hip_bfloat16;

__device__ __forceinline__ float ldx(const void* p, size_t i, bool f32) {
    return f32 ? ((const float*)p)[i] : __bfloat162float(((const bf16*)p)[i]);
}
__device__ __forceinline__ void stx(void* p, size_t i, bool f32, float v) {
    if (f32) ((float*)p)[i] = v;
    else ((bf16*)p)[i] = __float2bfloat16(v);
}

__device__ __forceinline__ float softplus_f(float x) {
    return fmaxf(x, 0.f) + __logf(1.f + __expf(-fabsf(x)));
}
__device__ __forceinline__ float sigmoid_f(float x) {
    return 1.f / (1.f + __expf(-x));
}

// ---------------------------------------------------------------------------
// Detect input dtype. state_embedding ~ N(0,1). Interpret first 256 uint16
// words; for even-indexed words compute bf16 exponent field. True bf16 data:
// exponents in ~[110,130]. fp32 data: even words are fp32 low-mantissa junk,
// exponent ~uniform -> mostly outside [100,140]. flag=1 means fp32.
// ---------------------------------------------------------------------------
__global__ void detect_k(const unsigned short* __restrict__ raw, int* flag) {
    if (threadIdx.x == 0 && blockIdx.x == 0) {
        int weird = 0;
        for (int i = 0; i < 256; i += 2) {
            int e = (raw[i] >> 7) & 0xFF;
            if (e > 140 || e < 100) weird++;
        }
        *flag = (weird > 32) ? 1 : 0;
    }
}

// ---------------------------------------------------------------------------
// Wsum[j2, n] = sum_t Wref[(t*227 + 163 + j2), n],  j2 < 64, n < 227  (f32)
// ---------------------------------------------------------------------------
__global__ __launch_bounds__(256) void prep_wsum(const void* __restrict__ Wref,
                                                 float* __restrict__ Wsum,
                                                 const int* __restrict__ flagp) {
    const bool f32 = (*flagp != 0);
    int idx = blockIdx.x * 256 + threadIdx.x;
    if (idx >= 64 * 227) return;
    int j2 = idx / 227;
    int n = idx - j2 * 227;
    float s = 0.f;
    for (int t = 0; t < 35; t++)
        s += ldx(Wref, (size_t)(t * 227 + 163 + j2) * 227 + n, f32);
    Wsum[j2 * 227 + n] = s;
}

// ---------------------------------------------------------------------------
// Tiled GEMM: C[M,N] = act(A[M,K] @ W[K,N] + bias), C is f32 workspace.
// AMODE 0: A is f32 workspace (c0 ignored must be 0 offset rows baked in ptr? no:
//          A indexed (m0+ar)*lda + k).  AMODE 1: A is flag-typed input, row
//          offset c0 added.
// ---------------------------------------------------------------------------
template <int AMODE, int ACT>
__global__ __launch_bounds__(256) void gemm_k(
    const void* __restrict__ A, int lda, int c0,
    const void* __restrict__ W, int ldw,
    const void* __restrict__ bias,
    float* __restrict__ C, int ldc,
    int M, int N, int K,
    const int* __restrict__ flagp) {
    __shared__ __align__(16) float As[16 * 68];  // [k][m], padded
    __shared__ __align__(16) float Ws[16 * 64];  // [k][n]

    const bool f32 = (*flagp != 0);
    const int tid = threadIdx.x;
    const int n0 = blockIdx.x * 64;
    const int m0 = blockIdx.y * 64;
    const int tx = tid & 15;
    const int ty = tid >> 4;
    const int ar = tid >> 2;
    const int ac0 = (tid & 3) * 4;
    const int wr = tid >> 4;
    const int wc0 = (tid & 15) * 4;

    float acc[4][4];
#pragma unroll
    for (int i = 0; i < 4; i++)
#pragma unroll
        for (int j = 0; j < 4; j++) acc[i][j] = 0.f;

    for (int k0 = 0; k0 < K; k0 += 16) {
#pragma unroll
        for (int i = 0; i < 4; i++) {
            int k = k0 + ac0 + i;
            float v = 0.f;
            if (k < K) {
                if (AMODE == 0) v = ((const float*)A)[(size_t)(m0 + ar) * lda + k];
                else v = ldx(A, (size_t)(c0 + m0 + ar) * lda + k, f32);
            }
            As[(ac0 + i) * 68 + ar] = v;
        }
        {
            int k = k0 + wr;
#pragma unroll
            for (int i = 0; i < 4; i++) {
                int n = n0 + wc0 + i;
                float v = 0.f;
                if (k < K && n < N) v = ldx(W, (size_t)k * ldw + n, f32);
                Ws[wr * 64 + wc0 + i] = v;
            }
        }
        __syncthreads();
#pragma unroll
        for (int kk = 0; kk < 16; kk++) {
            const float4 a4 = *(const float4*)&As[kk * 68 + ty * 4];
            const float4 w4 = *(const float4*)&Ws[kk * 64 + tx * 4];
            float av[4] = {a4.x, a4.y, a4.z, a4.w};
            float wv[4] = {w4.x, w4.y, w4.z, w4.w};
#pragma unroll
            for (int i = 0; i < 4; i++)
#pragma unroll
                for (int j = 0; j < 4; j++)
                    acc[i][j] = fmaf(av[i], wv[j], acc[i][j]);
        }
        __syncthreads();
    }

#pragma unroll
    for (int i = 0; i < 4; i++) {
        int gm = m0 + ty * 4 + i;
#pragma unroll
        for (int j = 0; j < 4; j++) {
            int gn = n0 + tx * 4 + j;
            if (gn < N) {
                float v = acc[i][j];
                if (bias) v += ldx(bias, gn, f32);
                if (ACT == 1) v = softplus_f(v);
                C[(size_t)gm * ldc + gn] = v;
            }
        }
    }
}

// ---------------------------------------------------------------------------
// Encoder GEMM: fin[MC,227] = [se | pz] @ W_cat, reading W_ref in-place.
//   k < 5705 : A col from se (ld 5705), W row = k + 64*(k/163) of Wref
//   k >= 5705: A col from pz (ld 64),   W row = Wsum[k-5705] (f32)
// ---------------------------------------------------------------------------
__global__ __launch_bounds__(256) void gemm_cat_k(
    const void* __restrict__ se, const void* __restrict__ pz,
    const void* __restrict__ Wref, const float* __restrict__ Wsum,
    float* __restrict__ C, int M, int c0,
    const int* __restrict__ flagp) {
    __shared__ __align__(16) float As[16 * 68];
    __shared__ __align__(16) float Ws[16 * 64];

    const bool f32 = (*flagp != 0);
    const int K = 5769, K1 = 5705, N = 227;
    const int tid = threadIdx.x;
    const int n0 = blockIdx.x * 64;
    const int m0 = blockIdx.y * 64;
    const int tx = tid & 15;
    const int ty = tid >> 4;
    const int ar = tid >> 2;
    const int ac0 = (tid & 3) * 4;
    const int wr = tid >> 4;
    const int wc0 = (tid & 15) * 4;

    float acc[4][4];
#pragma unroll
    for (int i = 0; i < 4; i++)
#pragma unroll
        for (int j = 0; j < 4; j++) acc[i][j] = 0.f;

    for (int k0 = 0; k0 < K; k0 += 16) {
#pragma unroll
        for (int i = 0; i < 4; i++) {
            int k = k0 + ac0 + i;
            float v = 0.f;
            if (k < K1) v = ldx(se, (size_t)(c0 + m0 + ar) * 5705 + k, f32);
            else if (k < K) v = ldx(pz, (size_t)(c0 + m0 + ar) * 64 + (k - K1), f32);
            As[(ac0 + i) * 68 + ar] = v;
        }
        {
            int k = k0 + wr;
#pragma unroll
            for (int i = 0; i < 4; i++) {
                int n = n0 + wc0 + i;
                float v = 0.f;
                if (n < N) {
                    if (k < K1) {
                        int wrow = k + 64 * (k / 163);
                        v = ldx(Wref, (size_t)wrow * 227 + n, f32);
                    } else if (k < K) {
                        v = Wsum[(k - K1) * 227 + n];
                    }
                }
                Ws[wr * 64 + wc0 + i] = v;
            }
        }
        __syncthreads();
#pragma unroll
        for (int kk = 0; kk < 16; kk++) {
            const float4 a4 = *(const float4*)&As[kk * 68 + ty * 4];
            const float4 w4 = *(const float4*)&Ws[kk * 64 + tx * 4];
            float av[4] = {a4.x, a4.y, a4.z, a4.w};
            float wv[4] = {w4.x, w4.y, w4.z, w4.w};
#pragma unroll
            for (int i = 0; i < 4; i++)
#pragma unroll
                for (int j = 0; j < 4; j++)
                    acc[i][j] = fmaf(av[i], wv[j], acc[i][j]);
        }
        __syncthreads();
    }

#pragma unroll
    for (int i = 0; i < 4; i++) {
        int gm = m0 + ty * 4 + i;
#pragma unroll
        for (int j = 0; j < 4; j++) {
            int gn = n0 + tx * 4 + j;
            if (gn < N) C[(size_t)gm * 227 + gn] = acc[i][j];
        }
    }
}

// ---------------------------------------------------------------------------
// g-net: out[r,62+d] = sigmoid( sum_h sp(x*gW1[d,h]+gb1[d,h]) * gW2[d,h] + gb2[d] )
// ---------------------------------------------------------------------------
__global__ __launch_bounds__(256) void g_kernel(
    const float* __restrict__ flat,
    const void* __restrict__ gW1, const void* __restrict__ gb1,
    const void* __restrict__ gW2, const void* __restrict__ gb2,
    void* __restrict__ out, int c0,
    const int* __restrict__ flagp) {
    __shared__ float w1[227], b1[227], w2[227];
    const bool f32 = (*flagp != 0);
    const int d = blockIdx.x;
    const int t = threadIdx.x;
    const int b = blockIdx.y * 256 + t;
    if (t < 227) {
        w1[t] = ldx(gW1, (size_t)d * 227 + t, f32);
        b1[t] = ldx(gb1, (size_t)d * 227 + t, f32);
        w2[t] = ldx(gW2, (size_t)d * 227 + t, f32);
    }
    __syncthreads();
    float x = flat[(size_t)b * 227 + d];
    float acc = ldx(gb2, d, f32);
    for (int h = 0; h < 227; h++) {
        float z = fmaf(x, w1[h], b1[h]);
        acc = fmaf(softplus_f(z), w2[h], acc);
    }
    stx(out, (size_t)(c0 + b) * 415 + 62 + d, f32, sigmoid_f(acc));
}

// ---------------------------------------------------------------------------
__device__ __forceinline__ float lse12(const float* s) {
    float m = s[0];
#pragma unroll
    for (int j = 1; j < 12; j++) m = fmaxf(m, s[j]);
    float sum = 0.f;
#pragma unroll
    for (int j = 0; j < 12; j++) sum += __expf(s[j] - m);
    return m + __logf(sum);
}

__global__ __launch_bounds__(256) void heads_k(
    const float* __restrict__ flat, const float* __restrict__ ctx,
    const void* __restrict__ Wl, const void* __restrict__ Wsh, const void* __restrict__ Wm,
    const void* __restrict__ cWl, const void* __restrict__ cWsh, const void* __restrict__ cWm,
    void* __restrict__ out, int c0,
    const int* __restrict__ flagp) {
    __shared__ float fl[227];
    __shared__ float cx[64];
    __shared__ float sraw[12], craw[12];
    __shared__ float lsf, lsc;
    const bool f32 = (*flagp != 0);
    const int b = blockIdx.x;
    const int t = threadIdx.x;
    if (t < 227) fl[t] = flat[(size_t)b * 227 + t];
    if (t < 64) cx[t] = ctx[(size_t)b * 64 + t];
    __syncthreads();
    const size_t ro = (size_t)(c0 + b) * 415;

    if (t < 25) {
        float a = 0.f;
        for (int k = 0; k < 227; k++) a = fmaf(fl[k], ldx(Wl, (size_t)k * 25 + t, f32), a);
        stx(out, ro + t, f32, a);
    } else if (t < 37) {
        int j = t - 25;
        float a = 0.f;
        for (int k = 0; k < 227; k++) a = fmaf(fl[k], ldx(Wsh, (size_t)k * 12 + j, f32), a);
        sraw[j] = a;
    } else if (t < 62) {
        int j = t - 37;
        float a = 0.f;
        for (int k = 0; k < 227; k++) a = fmaf(fl[k], ldx(Wm, (size_t)k * 25 + j, f32), a);
        stx(out, ro + 37 + j, f32, a);
    } else if (t >= 64 && t < 126) {
        int j2 = t - 64;
        if (j2 < 25) {
            float a = 0.f;
            for (int k = 0; k < 64; k++) a = fmaf(cx[k], ldx(cWl, (size_t)k * 25 + j2, f32), a);
            stx(out, ro + 289 + j2, f32, a);
        } else if (j2 < 37) {
            int j = j2 - 25;
            float a = 0.f;
            for (int k = 0; k < 64; k++) a = fmaf(cx[k], ldx(cWsh, (size_t)k * 12 + j, f32), a);
            craw[j] = a;
        } else {
            int j = j2 - 37;
            float a = 0.f;
            for (int k = 0; k < 64; k++) a = fmaf(cx[k], ldx(cWm, (size_t)k * 25 + j, f32), a);
            stx(out, ro + 326 + j, f32, a);
        }
    } else if (t >= 128 && t < 192) {
        stx(out, ro + 351 + (t - 128), f32, cx[t - 128]);
    }
    __syncthreads();
    if (t == 0) lsf = lse12(sraw);
    if (t == 64) lsc = lse12(craw);
    __syncthreads();
    if (t < 12) stx(out, ro + 25 + t, f32, sraw[t] - lsf);
    else if (t >= 64 && t < 76) stx(out, ro + 314 + (t - 64), f32, craw[t - 64] - lsc);
}

// ---------------------------------------------------------------------------
extern "C" void kernel_launch(void* const* d_in, const int* in_sizes, int n_in,
                              void* d_out, int out_size, void* d_ws, size_t ws_size,
                              hipStream_t stream) {
    const void* se    = d_in[0];   // [4096,35,163]
    const void* pz    = d_in[1];   // [4096,64]
    const void* Wref  = d_in[2];   // [7945,227]
    const void* fW1   = d_in[3];
    const void* fb1   = d_in[4];
    const void* fW2   = d_in[5];
    const void* fb2   = d_in[6];
    const void* fW3   = d_in[7];
    const void* fb3   = d_in[8];
    const void* gW1   = d_in[9];
    const void* gb1   = d_in[10];
    const void* gW2   = d_in[11];
    const void* gb2   = d_in[12];
    const void* Wland = d_in[13];
    const void* Wshot = d_in[14];
    const void* Wmove = d_in[15];
    const void* cW1   = d_in[16];
    const void* cb1   = d_in[17];
    const void* cW2   = d_in[18];
    const void* cb2   = d_in[19];
    const void* cW3   = d_in[20];
    const void* cb3   = d_in[21];
    const void* cWl   = d_in[22];
    const void* cWs   = d_in[23];
    const void* cWm   = d_in[24];

    // ---- workspace: flag(16) + Wsum(58112,pad to 58352) + per-row 8448 B ----
    int MC = 256;
    {
        const int cand[5] = {4096, 2048, 1024, 512, 256};
        for (int i = 0; i < 5; i++) {
            size_t need = 58368 + (size_t)cand[i] * 8448;
            if (need <= ws_size) { MC = cand[i]; break; }
        }
    }

    char* base = (char*)d_ws;
    int* flag   = (int*)base;                                   // 16 B
    float* Wsum = (float*)(base + 16);                          // 58112 B
    float* h1   = (float*)(base + 58368);                       // MC*1024 f32
    float* h2   = (float*)(base + 58368 + (size_t)MC * 4096);   // MC*1024 f32
    float* ctxb = (float*)(base + 58368 + (size_t)MC * 8192);   // MC*64 f32
    float* fin  = h2;   // MC*227 f32 (aliases h2; h2 dead)
    float* flat = h1;   // MC*227 f32 (aliases h1; h1 dead)

    detect_k<<<1, 64, 0, stream>>>((const unsigned short*)se, flag);
    prep_wsum<<<dim3(57), 256, 0, stream>>>(Wref, Wsum, flag);

    for (int c0 = 0; c0 < 4096; c0 += MC) {
        dim3 gH(16, MC / 64), g64(1, MC / 64), gD(4, MC / 64);

        // context chain: h1 = sp(pz@cW1+b); h2 = sp(h1@cW2+b); ctxb = h2@cW3+b
        gemm_k<1, 1><<<gH, 256, 0, stream>>>(pz, 64, c0, cW1, 1024, cb1,
                                             h1, 1024, MC, 1024, 64, flag);
        gemm_k<0, 1><<<gH, 256, 0, stream>>>(h1, 1024, 0, cW2, 1024, cb2,
                                             h2, 1024, MC, 1024, 1024, flag);
        gemm_k<0, 0><<<g64, 256, 0, stream>>>(h2, 1024, 0, cW3, 64, cb3,
                                              ctxb, 64, MC, 64, 1024, flag);

        // encoder GEMM -> fin (aliases h2, which is now dead)
        gemm_cat_k<<<gD, 256, 0, stream>>>(se, pz, Wref, Wsum, fin, MC, c0, flag);

        // f-decoder chain: h1 = sp(fin@fW1+b); h2 = sp(h1@fW2+b); flat = h2@fW3+b
        gemm_k<0, 1><<<gH, 256, 0, stream>>>(fin, 227, 0, fW1, 1024, fb1,
                                             h1, 1024, MC, 1024, 227, flag);
        gemm_k<0, 1><<<gH, 256, 0, stream>>>(h1, 1024, 0, fW2, 1024, fb2,
                                             h2, 1024, MC, 1024, 1024, flag);
        gemm_k<0, 0><<<gD, 256, 0, stream>>>(h2, 1024, 0, fW3, 227, fb3,
                                             flat, 227, MC, 227, 1024, flag);

        // g-net + heads
        g_kernel<<<dim3(227, MC / 256), 256, 0, stream>>>(flat, gW1, gb1, gW2, gb2,
                                                          d_out, c0, flag);
        heads_k<<<dim3(MC), 256, 0, stream>>>(flat, ctxb, Wland, Wshot, Wmove,
                                              cWl, cWs, cWm, d_out, c0, flag);
    }
}

// Round 4
// 877.618 us; speedup vs baseline: 2.5389x; 2.5389x over previous
//
#include <hip/hip_runtime.h>
#include <hip/hip_bf16.h>

using s8 = __attribute__((ext_vector_type(8))) short;
using f4 = __attribute__((ext_vector_type(4))) float;

__device__ __forceinline__ unsigned short f2b(float f) {
    union { float f; unsigned u; } v; v.f = f;
    unsigned r = v.u + 0x7fffu + ((v.u >> 16) & 1u);
    return (unsigned short)(r >> 16);
}
__device__ __forceinline__ float b2f(unsigned short u) {
    union { unsigned u; float f; } v; v.u = ((unsigned)u) << 16;
    return v.f;
}
__device__ __forceinline__ float softplus_f(float x) {
    return fmaxf(x, 0.f) + __logf(1.f + __expf(-fabsf(x)));
}
__device__ __forceinline__ float sigmoid_f(float x) {
    return 1.f / (1.f + __expf(-x));
}

// ---------------------------------------------------------------------------
// Tiled transpose + f32->bf16: dst[n][k] = src[k][n].  dst ld = ldst.
// block (32,8), grid (ceil(N/32), ceil(K/32)).
// ---------------------------------------------------------------------------
__global__ __launch_bounds__(256) void transpose_w(const float* __restrict__ src,
                                                   unsigned short* __restrict__ dst,
                                                   int K, int N, int ldst) {
    __shared__ float tile[32][33];
    const int n0 = blockIdx.x * 32, k0 = blockIdx.y * 32;
    const int tx = threadIdx.x, ty = threadIdx.y;
#pragma unroll
    for (int r = 0; r < 4; r++) {
        int k = k0 + ty + r * 8, n = n0 + tx;
        tile[ty + r * 8][tx] = (k < K && n < N) ? src[(size_t)k * N + n] : 0.f;
    }
    __syncthreads();
#pragma unroll
    for (int r = 0; r < 4; r++) {
        int n = n0 + ty + r * 8, k = k0 + tx;
        if (n < N && k < K) dst[(size_t)n * ldst + k] = f2b(tile[tx][ty + r * 8]);
    }
}

// ---------------------------------------------------------------------------
// WcatT[n][k] (bf16, ld 5776): k<5705 -> Wref[k + 64*(k/163)][n];
//                              k>=5705 -> sum_t Wref[t*227+163+(k-5705)][n]
// grid (8, 181), block (32,8)
// ---------------------------------------------------------------------------
__global__ __launch_bounds__(256) void wcat_t(const float* __restrict__ Wref,
                                              unsigned short* __restrict__ dst) {
    __shared__ float tile[32][33];
    const int n0 = blockIdx.x * 32, k0 = blockIdx.y * 32;
    const int tx = threadIdx.x, ty = threadIdx.y;
#pragma unroll
    for (int r = 0; r < 4; r++) {
        int k = k0 + ty + r * 8, n = n0 + tx;
        float v = 0.f;
        if (k < 5769 && n < 227) {
            if (k < 5705) {
                int wrow = k + 64 * (k / 163);
                v = Wref[(size_t)wrow * 227 + n];
            } else {
                int j2 = k - 5705;
                for (int t = 0; t < 35; t++)
                    v += Wref[(size_t)(t * 227 + 163 + j2) * 227 + n];
            }
        }
        tile[ty + r * 8][tx] = v;
    }
    __syncthreads();
#pragma unroll
    for (int r = 0; r < 4; r++) {
        int n = n0 + ty + r * 8, k = k0 + tx;
        if (n < 227 && k < 5769) dst[(size_t)n * 5776 + k] = f2b(tile[tx][ty + r * 8]);
    }
}

// ---------------------------------------------------------------------------
// Prefill: fin[4096*228]=0; flat[4096*228]=fb3[col]; ctx[4096*64]=cb3[col]
// ---------------------------------------------------------------------------
__global__ __launch_bounds__(256) void prefill_k(float* __restrict__ fin,
                                                 float* __restrict__ flat,
                                                 float* __restrict__ ctx,
                                                 const float* __restrict__ fb3,
                                                 const float* __restrict__ cb3) {
    const int S1 = 4096 * 228, S3 = 4096 * 64;
    int id = blockIdx.x * 256 + threadIdx.x;
    if (id < S1) {
        fin[id] = 0.f;
        int col = id % 228;
        flat[id] = (col < 227) ? fb3[col] : 0.f;
    } else {
        int j = id - S1;
        if (j < S3) ctx[j] = cb3[j & 63];
    }
}

// ---------------------------------------------------------------------------
// MFMA GEMM: C[M,N] (+)= act(A[M,K] @ WT^T + bias)
// WT is bf16 [N][K] row-major (ld ldwt). 128x128 tile, BK=32, 4 waves,
// each wave 64x64 via 4x4 frags of v_mfma_f32_16x16x32_bf16.
// AMODE: 0 = A fp32 (lda), 1 = A bf16/ushort (lda), 2 = concat se|pz fp32.
// ATOMIC: atomicAdd f32 partials (split-K via grid.z); else bias+act+store.
// ---------------------------------------------------------------------------
template <int AMODE, int ACT, bool ATOMIC, bool OBF16>
__global__ __launch_bounds__(256) void gemm_mfma(
    const void* __restrict__ Aptr, int lda,
    const float* __restrict__ A2ptr,           // pz (concat only)
    const unsigned short* __restrict__ WT, int ldwt,
    const float* __restrict__ bias,
    void* __restrict__ Cptr, int ldc,
    int M, int N, int K, int kchunk) {
    __shared__ unsigned short As[128 * 40];
    __shared__ unsigned short Bs[128 * 40];

    const int tid = threadIdx.x;
    const int m0 = blockIdx.y * 128, n0 = blockIdx.x * 128;
    const int kbeg = blockIdx.z * kchunk;
    const int kend = min(kbeg + kchunk, K);
    const int lane = tid & 63, w = tid >> 6;
    const int wm = w >> 1, wn = w & 1;
    const int quad = lane >> 4, l16 = lane & 15;

    f4 acc[4][4] = {};

    for (int k0 = kbeg; k0 < kend; k0 += 32) {
        const bool full = (kend - k0) >= 32;
        // ---- stage A tile: rows m0..m0+127, k0..k0+31 -> As[row][k] bf16 ----
#pragma unroll
        for (int i = 0; i < 4; i++) {
            int f = tid + i * 256;
            int r = f >> 3, cc = (f & 7) * 4;
            int gm = m0 + r;
            ushort4 val;
            if (AMODE == 0) {
                const float* A = (const float*)Aptr;
                if (full) {
                    float4 v = *(const float4*)(A + (size_t)gm * lda + k0 + cc);
                    val.x = f2b(v.x); val.y = f2b(v.y); val.z = f2b(v.z); val.w = f2b(v.w);
                } else {
                    float t[4];
#pragma unroll
                    for (int j = 0; j < 4; j++) {
                        int k = k0 + cc + j;
                        t[j] = (k < kend) ? A[(size_t)gm * lda + k] : 0.f;
                    }
                    val.x = f2b(t[0]); val.y = f2b(t[1]); val.z = f2b(t[2]); val.w = f2b(t[3]);
                }
            } else if (AMODE == 1) {
                const unsigned short* A = (const unsigned short*)Aptr;
                if (full) {
                    val = *(const ushort4*)(A + (size_t)gm * lda + k0 + cc);
                } else {
                    unsigned short t[4];
#pragma unroll
                    for (int j = 0; j < 4; j++) {
                        int k = k0 + cc + j;
                        t[j] = (k < kend) ? A[(size_t)gm * lda + k] : (unsigned short)0;
                    }
                    val.x = t[0]; val.y = t[1]; val.z = t[2]; val.w = t[3];
                }
            } else {
                const float* se = (const float*)Aptr;
                float t[4];
#pragma unroll
                for (int j = 0; j < 4; j++) {
                    int k = k0 + cc + j;
                    float v = 0.f;
                    if (k < kend) {
                        v = (k < 5705) ? se[(size_t)gm * 5705 + k]
                                       : A2ptr[(size_t)gm * 64 + (k - 5705)];
                    }
                    t[j] = v;
                }
                val.x = f2b(t[0]); val.y = f2b(t[1]); val.z = f2b(t[2]); val.w = f2b(t[3]);
            }
            *(ushort4*)&As[r * 40 + cc] = val;
        }
        // ---- stage W tile: WT rows n0..n0+127 (bf16), k0..k0+31 ----
#pragma unroll
        for (int i = 0; i < 4; i++) {
            int f = tid + i * 256;
            int r = f >> 3, cc = (f & 7) * 4;
            int gn = n0 + r;
            ushort4 val;
            if (gn < N) {
                if (full) {
                    val = *(const ushort4*)(WT + (size_t)gn * ldwt + k0 + cc);
                } else {
                    unsigned short t[4];
#pragma unroll
                    for (int j = 0; j < 4; j++) {
                        int k = k0 + cc + j;
                        t[j] = (k < kend) ? WT[(size_t)gn * ldwt + k] : (unsigned short)0;
                    }
                    val.x = t[0]; val.y = t[1]; val.z = t[2]; val.w = t[3];
                }
            } else {
                val.x = val.y = val.z = val.w = 0;
            }
            *(ushort4*)&Bs[r * 40 + cc] = val;
        }
        __syncthreads();
        // ---- compute: 16 MFMA ----
        s8 a[4], b[4];
#pragma unroll
        for (int mi = 0; mi < 4; mi++)
            a[mi] = *(const s8*)&As[(wm * 64 + mi * 16 + l16) * 40 + quad * 8];
#pragma unroll
        for (int ni = 0; ni < 4; ni++)
            b[ni] = *(const s8*)&Bs[(wn * 64 + ni * 16 + l16) * 40 + quad * 8];
#pragma unroll
        for (int mi = 0; mi < 4; mi++)
#pragma unroll
            for (int ni = 0; ni < 4; ni++)
                acc[mi][ni] = __builtin_amdgcn_mfma_f32_16x16x32_bf16(
                    a[mi], b[ni], acc[mi][ni], 0, 0, 0);
        __syncthreads();
    }

    // ---- epilogue: D[row=quad*4+r][col=l16] per frag ----
#pragma unroll
    for (int mi = 0; mi < 4; mi++) {
        int gmb = m0 + wm * 64 + mi * 16 + quad * 4;
#pragma unroll
        for (int ni = 0; ni < 4; ni++) {
            int gn = n0 + wn * 64 + ni * 16 + l16;
            if (gn < N) {
#pragma unroll
                for (int r = 0; r < 4; r++) {
                    float v = acc[mi][ni][r];
                    size_t off = (size_t)(gmb + r) * ldc + gn;
                    if (ATOMIC) {
                        atomicAdd((float*)Cptr + off, v);
                    } else {
                        if (bias) v += bias[gn];
                        if (ACT == 1) v = softplus_f(v);
                        if (OBF16) ((unsigned short*)Cptr)[off] = f2b(v);
                        else ((float*)Cptr)[off] = v;
                    }
                }
            }
        }
    }
}

// ---------------------------------------------------------------------------
// g-net: out[b,62+d] = sigmoid( sum_h sp(x*gW1[d,h]+gb1[d,h]) * gW2[d,h] + gb2[d] )
// ---------------------------------------------------------------------------
__global__ __launch_bounds__(256) void g_kernel(
    const float* __restrict__ flat,
    const float* __restrict__ gW1, const float* __restrict__ gb1,
    const float* __restrict__ gW2, const float* __restrict__ gb2,
    float* __restrict__ out) {
    __shared__ float w1[227], b1[227], w2[227];
    const int d = blockIdx.x;
    const int t = threadIdx.x;
    const int b = blockIdx.y * 256 + t;
    if (t < 227) {
        w1[t] = gW1[(size_t)d * 227 + t];
        b1[t] = gb1[(size_t)d * 227 + t];
        w2[t] = gW2[(size_t)d * 227 + t];
    }
    __syncthreads();
    float x = flat[(size_t)b * 228 + d];
    float acc = gb2[d];
    for (int h = 0; h < 227; h++) {
        float z = fmaf(x, w1[h], b1[h]);
        acc = fmaf(softplus_f(z), w2[h], acc);
    }
    out[(size_t)b * 415 + 62 + d] = sigmoid_f(acc);
}

// ---------------------------------------------------------------------------
__device__ __forceinline__ float lse12(const float* s) {
    float m = s[0];
#pragma unroll
    for (int j = 1; j < 12; j++) m = fmaxf(m, s[j]);
    float sum = 0.f;
#pragma unroll
    for (int j = 0; j < 12; j++) sum += __expf(s[j] - m);
    return m + __logf(sum);
}

__global__ __launch_bounds__(256) void heads_k(
    const float* __restrict__ flat, const float* __restrict__ ctx,
    const float* __restrict__ Wl, const float* __restrict__ Wsh, const float* __restrict__ Wm,
    const float* __restrict__ cWl, const float* __restrict__ cWsh, const float* __restrict__ cWm,
    float* __restrict__ out) {
    __shared__ float fl[227];
    __shared__ float cx[64];
    __shared__ float sraw[12], craw[12];
    __shared__ float lsf, lsc;
    const int b = blockIdx.x;
    const int t = threadIdx.x;
    if (t < 227) fl[t] = flat[(size_t)b * 228 + t];
    if (t < 64) cx[t] = ctx[(size_t)b * 64 + t];
    __syncthreads();
    float* ob = out + (size_t)b * 415;

    if (t < 25) {
        float a = 0.f;
        for (int k = 0; k < 227; k++) a = fmaf(fl[k], Wl[(size_t)k * 25 + t], a);
        ob[t] = a;
    } else if (t < 37) {
        int j = t - 25;
        float a = 0.f;
        for (int k = 0; k < 227; k++) a = fmaf(fl[k], Wsh[(size_t)k * 12 + j], a);
        sraw[j] = a;
    } else if (t < 62) {
        int j = t - 37;
        float a = 0.f;
        for (int k = 0; k < 227; k++) a = fmaf(fl[k], Wm[(size_t)k * 25 + j], a);
        ob[37 + j] = a;
    } else if (t >= 64 && t < 126) {
        int j2 = t - 64;
        if (j2 < 25) {
            float a = 0.f;
            for (int k = 0; k < 64; k++) a = fmaf(cx[k], cWl[(size_t)k * 25 + j2], a);
            ob[289 + j2] = a;
        } else if (j2 < 37) {
            int j = j2 - 25;
            float a = 0.f;
            for (int k = 0; k < 64; k++) a = fmaf(cx[k], cWsh[(size_t)k * 12 + j], a);
            craw[j] = a;
        } else {
            int j = j2 - 37;
            float a = 0.f;
            for (int k = 0; k < 64; k++) a = fmaf(cx[k], cWm[(size_t)k * 25 + j], a);
            ob[326 + j] = a;
        }
    } else if (t >= 128 && t < 192) {
        ob[351 + (t - 128)] = cx[t - 128];
    }
    __syncthreads();
    if (t == 0) lsf = lse12(sraw);
    if (t == 64) lsc = lse12(craw);
    __syncthreads();
    if (t < 12) ob[25 + t] = sraw[t] - lsf;
    else if (t >= 64 && t < 76) ob[314 + (t - 64)] = craw[t - 64] - lsc;
}

// ---------------------------------------------------------------------------
extern "C" void kernel_launch(void* const* d_in, const int* in_sizes, int n_in,
                              void* d_out, int out_size, void* d_ws, size_t ws_size,
                              hipStream_t stream) {
    const float* se    = (const float*)d_in[0];   // [4096,35*163=5705]
    const float* pz    = (const float*)d_in[1];   // [4096,64]
    const float* Wref  = (const float*)d_in[2];   // [7945,227]
    const float* fW1   = (const float*)d_in[3];
    const float* fb1   = (const float*)d_in[4];
    const float* fW2   = (const float*)d_in[5];
    const float* fb2   = (const float*)d_in[6];
    const float* fW3   = (const float*)d_in[7];
    const float* fb3   = (const float*)d_in[8];
    const float* gW1   = (const float*)d_in[9];
    const float* gb1   = (const float*)d_in[10];
    const float* gW2   = (const float*)d_in[11];
    const float* gb2   = (const float*)d_in[12];
    const float* Wland = (const float*)d_in[13];
    const float* Wshot = (const float*)d_in[14];
    const float* Wmove = (const float*)d_in[15];
    const float* cW1   = (const float*)d_in[16];
    const float* cb1   = (const float*)d_in[17];
    const float* cW2   = (const float*)d_in[18];
    const float* cb2   = (const float*)d_in[19];
    const float* cW3   = (const float*)d_in[20];
    const float* cb3   = (const float*)d_in[21];
    const float* cWl   = (const float*)d_in[22];
    const float* cWs   = (const float*)d_in[23];
    const float* cWm   = (const float*)d_in[24];
    float* out = (float*)d_out;
    const int M = 4096;

    // ---- workspace layout (bytes, 256-aligned chunks); total ~31.8 MB ----
    char* p = (char*)d_ws;
    auto alloc = [&](size_t bytes) {
        char* r = p;
        p += (bytes + 255) & ~(size_t)255;
        return r;
    };
    unsigned short* WcatT = (unsigned short*)alloc((size_t)227 * 5776 * 2);
    unsigned short* cW1T  = (unsigned short*)alloc((size_t)1024 * 64 * 2);
    unsigned short* cW2T  = (unsigned short*)alloc((size_t)1024 * 1024 * 2);
    unsigned short* cW3T  = (unsigned short*)alloc((size_t)64 * 1024 * 2);
    unsigned short* fW1T  = (unsigned short*)alloc((size_t)1024 * 228 * 2);
    unsigned short* fW2T  = (unsigned short*)alloc((size_t)1024 * 1024 * 2);
    unsigned short* fW3T  = (unsigned short*)alloc((size_t)227 * 1024 * 2);
    unsigned short* h1    = (unsigned short*)alloc((size_t)M * 1024 * 2);
    unsigned short* h2    = (unsigned short*)alloc((size_t)M * 1024 * 2);
    float* fin  = (float*)alloc((size_t)M * 228 * 4);
    float* flat = (float*)alloc((size_t)M * 228 * 4);
    float* ctxb = (float*)alloc((size_t)M * 64 * 4);

    const dim3 tb(32, 8);
    // ---- weight prep (transpose + bf16) ----
    transpose_w<<<dim3(32, 2),  tb, 0, stream>>>(cW1, cW1T, 64, 1024, 64);
    transpose_w<<<dim3(32, 32), tb, 0, stream>>>(cW2, cW2T, 1024, 1024, 1024);
    transpose_w<<<dim3(2, 32),  tb, 0, stream>>>(cW3, cW3T, 1024, 64, 1024);
    transpose_w<<<dim3(32, 8),  tb, 0, stream>>>(fW1, fW1T, 227, 1024, 228);
    transpose_w<<<dim3(32, 32), tb, 0, stream>>>(fW2, fW2T, 1024, 1024, 1024);
    transpose_w<<<dim3(8, 32),  tb, 0, stream>>>(fW3, fW3T, 1024, 227, 1024);
    wcat_t<<<dim3(8, 181), tb, 0, stream>>>(Wref, WcatT);
    prefill_k<<<dim3((4096 * 228 + 4096 * 64 + 255) / 256), 256, 0, stream>>>(
        fin, flat, ctxb, fb3, cb3);

    // ---- context chain ----
    gemm_mfma<0, 1, false, true><<<dim3(8, 32, 1), 256, 0, stream>>>(
        pz, 64, nullptr, cW1T, 64, cb1, h1, 1024, M, 1024, 64, 64);
    gemm_mfma<1, 1, false, true><<<dim3(8, 32, 1), 256, 0, stream>>>(
        h1, 1024, nullptr, cW2T, 1024, cb2, h2, 1024, M, 1024, 1024, 1024);
    gemm_mfma<1, 0, true, false><<<dim3(1, 32, 8), 256, 0, stream>>>(
        h2, 1024, nullptr, cW3T, 1024, nullptr, ctxb, 64, M, 64, 1024, 128);

    // ---- encoder: fin = [se|pz] @ Wcat (split-K=6, atomic f32) ----
    gemm_mfma<2, 0, true, false><<<dim3(2, 32, 6), 256, 0, stream>>>(
        se, 5705, pz, WcatT, 5776, nullptr, fin, 228, M, 227, 5769, 992);

    // ---- f-decoder chain ----
    gemm_mfma<0, 1, false, true><<<dim3(8, 32, 1), 256, 0, stream>>>(
        fin, 228, nullptr, fW1T, 228, fb1, h1, 1024, M, 1024, 227, 227);
    gemm_mfma<1, 1, false, true><<<dim3(8, 32, 1), 256, 0, stream>>>(
        h1, 1024, nullptr, fW2T, 1024, fb2, h2, 1024, M, 1024, 1024, 1024);
    gemm_mfma<1, 0, true, false><<<dim3(2, 32, 4), 256, 0, stream>>>(
        h2, 1024, nullptr, fW3T, 1024, nullptr, flat, 228, M, 227, 1024, 256);

    // ---- g-net + heads ----
    g_kernel<<<dim3(227, 16), 256, 0, stream>>>(flat, gW1, gb1, gW2, gb2, out);
    heads_k<<<dim3(4096), 256, 0, stream>>>(flat, ctxb, Wland, Wshot, Wmove,
                                            cWl, cWs, cWm, out);
}